// Round 9
// baseline (8839.611 us; speedup 1.0000x reference)
//
#include <hip/hip_runtime.h>

typedef unsigned long long u64;
typedef float v2f __attribute__((ext_vector_type(2)));

#define FPS_N   8192
#define FPS_G   8              // blocks (CUs) per batch
#define FPS_T   256            // threads per block (4 waves)
#define FPS_W   (FPS_T / 64)   // 4 waves per block
#define FPS_SL  (FPS_G * FPS_W)        // 32 winner slots per batch
#define FPS_PPT (FPS_N / FPS_G / FPS_T) // 4 points per thread
#define FPS_PR  (FPS_PPT / 2)           // 2 packed pairs per thread

// Packed fp32 ops (VOP3P): two independent IEEE-RN f32 ops per instruction.
// asm-opaque -> no contraction/reassociation. Sub as a + (-c): bit-exact.
__device__ __forceinline__ v2f pk_add(v2f a, v2f b) {
    v2f r; asm("v_pk_add_f32 %0, %1, %2" : "=v"(r) : "v"(a), "v"(b)); return r;
}
__device__ __forceinline__ v2f pk_mul(v2f a, v2f b) {
    v2f r; asm("v_pk_mul_f32 %0, %1, %2" : "=v"(r) : "v"(a), "v"(b)); return r;
}
__device__ __forceinline__ v2f pk_fma(v2f a, v2f b, v2f c) {
    v2f r; asm("v_pk_fma_f32 %0, %1, %2, %3" : "=v"(r) : "v"(a), "v"(b), "v"(c)); return r;
}

// DPP max step; bound_ctrl=true -> OOB reads 0.0f (all values >= 0).
template<int CTRL>
__device__ __forceinline__ float dpp_max_step(float x) {
    int s = __builtin_amdgcn_update_dpp(0, __float_as_int(x), CTRL, 0xf, 0xf, true);
    return fmaxf(x, __int_as_float(s));
}
// Full wave64 max on the VALU pipe; broadcast from lane 63.
__device__ __forceinline__ float wave_max_nn(float x) {
    x = dpp_max_step<0x111>(x);  // row_shr:1
    x = dpp_max_step<0x112>(x);  // row_shr:2
    x = dpp_max_step<0x114>(x);  // row_shr:4
    x = dpp_max_step<0x118>(x);  // row_shr:8
    x = dpp_max_step<0x142>(x);  // row_bcast:15
    x = dpp_max_step<0x143>(x);  // row_bcast:31
    return __int_as_float(__builtin_amdgcn_readlane(__float_as_int(x), 63));
}

// Clears the sync slots between graph replays (stale tags would alias).
__global__ void zero_sync(u64* __restrict__ sync, int n) {
    int i = blockIdx.x * blockDim.x + threadIdx.x;
    if (i < n) sync[i] = 0ull;
}

// 8 blocks per batch, co-resident by construction (96KB LDS -> 1 block/CU,
// 128 blocks <= 256 CUs). Per iteration each wave leader publishes its
// winner as ONE relaxed agent-scope atomic u64:
//   [63:32] dist_bits | [25:13] idx | [12:0] seq = s+1   (payload==poll word)
// Parity double-buffer (slot[par][i]) makes the <=1-iteration skew safe:
// a block can only write parity p again after every block consumed the
// previous parity-p value (publish(s+1) happens after consume(s)).
// Distance math is the frozen XLA chain (bit-exact, R5/R7/R8-validated):
//   d = fma(dz,dz, fma(dy,dy, dx*dx))
// Ties: slot order == ascending point ranges; ballot+ctz -> smallest slot
// -> smallest global index == numpy first-occurrence.
__global__ __launch_bounds__(FPS_T) void fps_kernel(
    const float* __restrict__ coords,
    const int*   __restrict__ init_idx,
    int*         __restrict__ out_idx,
    u64*         __restrict__ sync,
    int M)
{
    __shared__ float sx[FPS_N], sy[FPS_N], sz[FPS_N];

    const int blk  = blockIdx.x;
    const int b    = blk / FPS_G;
    const int g    = blk - b * FPS_G;
    const int tid  = threadIdx.x;
    const int lane = tid & 63;
    const int wv   = tid >> 6;
    const int slot_id = g * FPS_W + wv;          // ascending with point range
    u64* syncb = sync + (size_t)b * 2 * FPS_SL;

    // Stage ALL coords into LDS (needed for far -> coords broadcast).
    // Thread t stages points t*32 .. t*32+31 (96 floats = 24 float4).
    const float4* cb4 = reinterpret_cast<const float4*>(coords + (size_t)b * FPS_N * 3);
    float f[96];
    #pragma unroll
    for (int i = 0; i < 24; ++i) {
        float4 v = cb4[tid * 24 + i];
        f[i*4+0] = v.x; f[i*4+1] = v.y; f[i*4+2] = v.z; f[i*4+3] = v.w;
    }
    const int sbase = tid * 32;
    #pragma unroll
    for (int k = 0; k < 32; ++k) {
        sx[sbase+k] = f[3*k+0]; sy[sbase+k] = f[3*k+1]; sz[sbase+k] = f[3*k+2];
    }
    __syncthreads();

    // Own 4 points (block g owns [g*1024, g*1024+1024)), packed in registers.
    const int base = g * (FPS_N / FPS_G) + tid * FPS_PPT;
    v2f px[FPS_PR], py[FPS_PR], pz[FPS_PR], dist[FPS_PR];
    #pragma unroll
    for (int j = 0; j < FPS_PR; ++j) {
        px[j] = v2f{sx[base+2*j], sx[base+2*j+1]};
        py[j] = v2f{sy[base+2*j], sy[base+2*j+1]};
        pz[j] = v2f{sz[base+2*j], sz[base+2*j+1]};
        dist[j] = v2f{1e8f, 1e8f};   // BIG, matches reference
    }

    int far = init_idx[b];
    float cx = sx[far], cy = sy[far], cz = sz[far];

    for (int s = 0; s < M; ++s) {
        if (g == 0 && tid == 0) out_idx[b * M + s] = far;  // record BEFORE update

        // --- distance update + thread max (math frozen) ---
        const v2f ncx = v2f{-cx, -cx};   // a + (-c) == a - c, bit-exact
        const v2f ncy = v2f{-cy, -cy};
        const v2f ncz = v2f{-cz, -cz};
        float m = 0.0f;
        #pragma unroll
        for (int j = 0; j < FPS_PR; ++j) {
            v2f dx2 = pk_add(px[j], ncx);
            v2f dy2 = pk_add(py[j], ncy);
            v2f dz2 = pk_add(pz[j], ncz);
            v2f d2  = pk_fma(dz2, dz2, pk_fma(dy2, dy2, pk_mul(dx2, dx2)));
            v2f nd;
            nd.x = fminf(dist[j].x, d2.x);
            nd.y = fminf(dist[j].y, d2.y);
            dist[j] = nd;
            m = fmaxf(m, fmaxf(nd.x, nd.y));
        }
        // first index achieving m (descending scan -> smallest wins)
        int myidx = base;
        #pragma unroll
        for (int j = FPS_PR - 1; j >= 0; --j) {
            myidx = (dist[j].y == m) ? base + 2*j + 1 : myidx;
            myidx = (dist[j].x == m) ? base + 2*j     : myidx;
        }

        // --- wave reduce (VALU pipe) ---
        float wm = wave_max_nn(m);
        u64 ball = __ballot(m == wm);
        int fl   = (int)__builtin_ctzll(ball);
        int widx = __builtin_amdgcn_readlane(myidx, fl);

        // --- publish: one relaxed agent-scope atomic u64, no fences ---
        const int par = s & 1;
        if (lane == 0) {
            u64 pk = ((u64)(unsigned)__float_as_uint(wm) << 32)
                   | ((u64)(unsigned)widx << 13)
                   | (u64)(unsigned)(s + 1);
            __hip_atomic_store(&syncb[par * FPS_SL + slot_id], pk,
                               __ATOMIC_RELAXED, __HIP_MEMORY_SCOPE_AGENT);
        }

        // --- poll all 32 slots: lane i owns slot i&31 (dup for 32-63) ---
        u64* pslot = &syncb[par * FPS_SL + (lane & (FPS_SL - 1))];
        const unsigned tag = (unsigned)(s + 1);
        u64 v;
        do {
            v = __hip_atomic_load(pslot, __ATOMIC_RELAXED, __HIP_MEMORY_SCOPE_AGENT);
        } while (!__all((unsigned)(v & 0x1FFFull) == tag));

        // --- global winner among 32 slots (first-occurrence ties) ---
        float cand = __int_as_float((int)(v >> 32));
        int   cidx = (int)((v >> 13) & 0x1FFF);
        float gm = wave_max_nn(cand);
        u64 b2 = __ballot(cand == gm);
        int l2 = (int)__builtin_ctzll(b2);      // smallest lane(<32) = smallest idx
        far = __builtin_amdgcn_readlane(cidx, l2);
        cx = sx[far]; cy = sy[far]; cz = sz[far];   // local LDS broadcast
    }
}

// One 64-thread block per output row: 64 x float4 = 256 floats of values,
// lanes 0-2 copy coords, lane 3 copies mask.
__global__ void gather_kernel(
    const float* __restrict__ coords,
    const float* __restrict__ values,
    const float* __restrict__ mask,
    const int*   __restrict__ idx,
    float* __restrict__ out_coords,
    float* __restrict__ out_values,
    float* __restrict__ out_mask,
    int N, int M, int D)
{
    const int bm = blockIdx.x;
    const int b  = bm / M;
    const int m  = bm - b * M;
    const int j  = idx[bm];
    const int l  = threadIdx.x;

    const float4* src = reinterpret_cast<const float4*>(values + ((size_t)b * N + j) * D);
    float4*       dst = reinterpret_cast<float4*>(out_values + ((size_t)b * M + m) * D);
    dst[l] = src[l];

    if (l < 3) {
        out_coords[((size_t)b * M + m) * 3 + l] = coords[((size_t)b * N + j) * 3 + l];
    } else if (l == 3) {
        out_mask[(size_t)b * M + m] = mask[(size_t)b * N + j];
    }
}

extern "C" void kernel_launch(void* const* d_in, const int* in_sizes, int n_in,
                              void* d_out, int out_size, void* d_ws, size_t ws_size,
                              hipStream_t stream)
{
    const float* coords   = (const float*)d_in[0];
    const float* values   = (const float*)d_in[1];
    const float* mask     = (const float*)d_in[2];
    const int*   init_idx = (const int*)d_in[3];

    const int B = in_sizes[3];
    const int N = in_sizes[2] / B;            // 8192
    const int D = in_sizes[1] / (B * N);      // 256
    const int M = N / 2;                      // SAMPLING_FRACTION = 0.5 -> 4096

    float* out_coords = (float*)d_out;
    float* out_values = out_coords + (size_t)B * M * 3;
    float* out_mask   = out_values + (size_t)B * M * D;

    int* idx  = (int*)d_ws;                                   // B*M ints = 256 KB
    u64* sync = (u64*)((char*)d_ws + (size_t)B * M * sizeof(int));
    const int nsync = B * 2 * FPS_SL;                         // 1024 u64 = 8 KB

    zero_sync<<<(nsync + 255) / 256, 256, 0, stream>>>(sync, nsync);
    fps_kernel<<<B * FPS_G, FPS_T, 0, stream>>>(coords, init_idx, idx, sync, M);
    gather_kernel<<<B * M, D / 4, 0, stream>>>(coords, values, mask, idx,
                                               out_coords, out_values, out_mask,
                                               N, M, D);
}

// Round 10
// 3727.708 us; speedup vs baseline: 2.3713x; 2.3713x over previous
//
#include <hip/hip_runtime.h>

typedef unsigned long long u64;
typedef float v2f __attribute__((ext_vector_type(2)));

#define FPS_N   8192
#define FPS_T   512
#define FPS_W   (FPS_T / 64)    // 8 waves
#define FPS_PPT (FPS_N / FPS_T) // 16 points per thread
#define FPS_PR  (FPS_PPT / 2)   // 8 packed pairs per thread

// Packed fp32 ops (VOP3P): two independent IEEE-RN f32 ops per instruction.
// asm-opaque -> no contraction/reassociation. Sub as a + (-c): bit-exact.
__device__ __forceinline__ v2f pk_add(v2f a, v2f b) {
    v2f r; asm("v_pk_add_f32 %0, %1, %2" : "=v"(r) : "v"(a), "v"(b)); return r;
}
__device__ __forceinline__ v2f pk_mul(v2f a, v2f b) {
    v2f r; asm("v_pk_mul_f32 %0, %1, %2" : "=v"(r) : "v"(a), "v"(b)); return r;
}
__device__ __forceinline__ v2f pk_fma(v2f a, v2f b, v2f c) {
    v2f r; asm("v_pk_fma_f32 %0, %1, %2, %3" : "=v"(r) : "v"(a), "v"(b), "v"(c)); return r;
}

// DPP max step; bound_ctrl=true -> OOB reads 0.0f (all values >= 0).
template<int CTRL>
__device__ __forceinline__ float dpp_max_step(float x) {
    int s = __builtin_amdgcn_update_dpp(0, __float_as_int(x), CTRL, 0xf, 0xf, true);
    return fmaxf(x, __int_as_float(s));
}
// Full wave64 max on the VALU pipe; broadcast from lane 63.
__device__ __forceinline__ float wave_max_nn(float x) {
    x = dpp_max_step<0x111>(x);  // row_shr:1
    x = dpp_max_step<0x112>(x);  // row_shr:2
    x = dpp_max_step<0x114>(x);  // row_shr:4
    x = dpp_max_step<0x118>(x);  // row_shr:8
    x = dpp_max_step<0x142>(x);  // row_bcast:15
    x = dpp_max_step<0x143>(x);  // row_bcast:31
    return __int_as_float(__builtin_amdgcn_readlane(__float_as_int(x), 63));
}
__device__ __forceinline__ float readlane_f(float x, int l) {
    return __int_as_float(__builtin_amdgcn_readlane(__float_as_int(x), l));
}

// One block per batch, 512 threads x 16 points, NO barrier in the loop.
// Cross-wave sync: parity-double-buffered LDS mailbox, one ds_write_b64 per
// wave per iteration:  [63:32]=dist_bits | [25:13]=idx | [12:0]=seq(s+1).
// Payload and tag share the atomic word -> relaxed-ish protocol is safe;
// 2-phase parity guarantees no slot is overwritten before all waves
// consumed it (publish(s+2, same parity) requires passing poll(s+1), which
// requires every wave published s+1, which requires they consumed s).
// Distance math is the frozen XLA chain (bit-exact, validated R5/R7/R8):
//   d = fma(dz,dz, fma(dy,dy, dx*dx))
// Ties: per-thread descending scan, per-wave ballot+ctz, per-block smallest
// slot via ballot+ctz (slot order == ascending point ranges) ==> exact
// numpy argmax first-occurrence semantics.
__global__ __launch_bounds__(FPS_T) void fps_kernel(
    const float* __restrict__ coords,
    const int*   __restrict__ init_idx,
    int*         __restrict__ out_idx,
    int M)
{
    __shared__ float sx[FPS_N], sy[FPS_N], sz[FPS_N];
    __shared__ u64 mbox[2][FPS_W];

    const int b    = blockIdx.x;
    const int tid  = threadIdx.x;
    const int lane = tid & 63;
    const int wv   = tid >> 6;
    const float* cb = coords + (size_t)b * FPS_N * 3;

    if (tid < 2 * FPS_W) ((u64*)mbox)[tid] = 0ull;   // no garbage tags

    // Load own 16 points: 48 contiguous floats = 12 float4 (coalesced)
    float f[48];
    const float4* cb4 = reinterpret_cast<const float4*>(cb);
    #pragma unroll
    for (int i = 0; i < 12; ++i) {
        float4 v = cb4[tid * 12 + i];
        f[i*4+0] = v.x; f[i*4+1] = v.y; f[i*4+2] = v.z; f[i*4+3] = v.w;
    }

    v2f px[FPS_PR], py[FPS_PR], pz[FPS_PR], dist[FPS_PR];
    const int base = tid * FPS_PPT;
    #pragma unroll
    for (int k = 0; k < FPS_PPT; ++k) {
        sx[base+k] = f[3*k+0]; sy[base+k] = f[3*k+1]; sz[base+k] = f[3*k+2];
    }
    #pragma unroll
    for (int j = 0; j < FPS_PR; ++j) {
        px[j] = v2f{f[6*j+0], f[6*j+3]};
        py[j] = v2f{f[6*j+1], f[6*j+4]};
        pz[j] = v2f{f[6*j+2], f[6*j+5]};
        dist[j] = v2f{1e8f, 1e8f};   // BIG, matches reference
    }
    __syncthreads();   // the only barrier: staging complete

    int far = init_idx[b];
    float cx = sx[far], cy = sy[far], cz = sz[far];

    for (int s = 0; s < M; ++s) {
        if (tid == 0) out_idx[b * M + s] = far;   // record BEFORE update
                                                  // (never drained in-loop)

        // --- distance update + thread max (math frozen) ---
        const v2f ncx = v2f{-cx, -cx};   // a + (-c) == a - c, bit-exact
        const v2f ncy = v2f{-cy, -cy};
        const v2f ncz = v2f{-cz, -cz};
        float m = 0.0f;
        #pragma unroll
        for (int j = 0; j < FPS_PR; ++j) {
            v2f dx2 = pk_add(px[j], ncx);
            v2f dy2 = pk_add(py[j], ncy);
            v2f dz2 = pk_add(pz[j], ncz);
            v2f d2  = pk_fma(dz2, dz2, pk_fma(dy2, dy2, pk_mul(dx2, dx2)));
            v2f nd;
            nd.x = fminf(dist[j].x, d2.x);
            nd.y = fminf(dist[j].y, d2.y);
            dist[j] = nd;
            m = fmaxf(m, fmaxf(nd.x, nd.y));
        }
        // first index achieving m (descending scan -> smallest wins)
        int myidx = base;
        #pragma unroll
        for (int j = FPS_PR - 1; j >= 0; --j) {
            myidx = (dist[j].y == m) ? base + 2*j + 1 : myidx;
            myidx = (dist[j].x == m) ? base + 2*j     : myidx;
        }

        // --- stage 1: wave reduce (VALU pipe) ---
        float wm = wave_max_nn(m);
        u64 ball = __ballot(m == wm);
        int fl   = (int)__builtin_ctzll(ball);
        int widx = __builtin_amdgcn_readlane(myidx, fl);

        // --- publish: one 8B LDS mailbox write per wave, release order ---
        const int par = s & 1;
        if (lane == 0) {
            u64 pk = ((u64)(unsigned)__float_as_uint(wm) << 32)
                   | ((u64)(unsigned)widx << 13)
                   | (u64)(unsigned)(s + 1);
            __hip_atomic_store(&mbox[par][wv], pk,
                               __ATOMIC_RELEASE, __HIP_MEMORY_SCOPE_WORKGROUP);
        }

        // --- poll the 8 slots (lane i -> slot i&7; same-addr broadcast) ---
        const unsigned tag = (unsigned)(s + 1);
        u64 v;
        do {
            v = __hip_atomic_load(&mbox[par][lane & (FPS_W - 1)],
                                  __ATOMIC_ACQUIRE, __HIP_MEMORY_SCOPE_WORKGROUP);
        } while (!__all((unsigned)(v & 0x1FFFull) == tag));

        // --- stage 2: reduce 8 candidates; speculative coord fetch ---
        float cand = __int_as_float((int)(v >> 32));
        int   cidx = (int)((v >> 13) & 0x1FFF);
        float fx = sx[cidx], fy = sy[cidx], fz = sz[cidx];  // overlaps reduce
        float gm = wave_max_nn(cand);
        u64 b2 = __ballot(cand == gm);
        int l2 = (int)__builtin_ctzll(b2);      // smallest slot = smallest idx
        far = __builtin_amdgcn_readlane(cidx, l2);
        cx  = readlane_f(fx, l2);
        cy  = readlane_f(fy, l2);
        cz  = readlane_f(fz, l2);
    }
}

// One 64-thread block per output row: 64 x float4 = 256 floats of values,
// lanes 0-2 copy coords, lane 3 copies mask.
__global__ void gather_kernel(
    const float* __restrict__ coords,
    const float* __restrict__ values,
    const float* __restrict__ mask,
    const int*   __restrict__ idx,
    float* __restrict__ out_coords,
    float* __restrict__ out_values,
    float* __restrict__ out_mask,
    int N, int M, int D)
{
    const int bm = blockIdx.x;
    const int b  = bm / M;
    const int m  = bm - b * M;
    const int j  = idx[bm];
    const int l  = threadIdx.x;

    const float4* src = reinterpret_cast<const float4*>(values + ((size_t)b * N + j) * D);
    float4*       dst = reinterpret_cast<float4*>(out_values + ((size_t)b * M + m) * D);
    dst[l] = src[l];

    if (l < 3) {
        out_coords[((size_t)b * M + m) * 3 + l] = coords[((size_t)b * N + j) * 3 + l];
    } else if (l == 3) {
        out_mask[(size_t)b * M + m] = mask[(size_t)b * N + j];
    }
}

extern "C" void kernel_launch(void* const* d_in, const int* in_sizes, int n_in,
                              void* d_out, int out_size, void* d_ws, size_t ws_size,
                              hipStream_t stream)
{
    const float* coords   = (const float*)d_in[0];
    const float* values   = (const float*)d_in[1];
    const float* mask     = (const float*)d_in[2];
    const int*   init_idx = (const int*)d_in[3];

    const int B = in_sizes[3];
    const int N = in_sizes[2] / B;            // 8192
    const int D = in_sizes[1] / (B * N);      // 256
    const int M = N / 2;                      // SAMPLING_FRACTION = 0.5 -> 4096

    float* out_coords = (float*)d_out;
    float* out_values = out_coords + (size_t)B * M * 3;
    float* out_mask   = out_values + (size_t)B * M * D;

    int* idx = (int*)d_ws;   // B*M ints = 256 KB scratch

    fps_kernel<<<B, FPS_T, 0, stream>>>(coords, init_idx, idx, M);
    gather_kernel<<<B * M, D / 4, 0, stream>>>(coords, values, mask, idx,
                                               out_coords, out_values, out_mask,
                                               N, M, D);
}

// Round 11
// 3506.718 us; speedup vs baseline: 2.5208x; 1.0630x over previous
//
#include <hip/hip_runtime.h>

typedef unsigned long long u64;
typedef float v2f __attribute__((ext_vector_type(2)));

#define FPS_N   8192
#define FPS_T   256
#define FPS_W   (FPS_T / 64)    // 4 waves, 1 per SIMD
#define FPS_PPT (FPS_N / FPS_T) // 32 points per thread
#define FPS_PR  (FPS_PPT / 2)   // 16 packed pairs per thread

// Packed fp32 ops (VOP3P): two independent IEEE-RN f32 ops per instruction.
// asm-opaque -> no contraction/reassociation. Sub as a + (-c): bit-exact.
__device__ __forceinline__ v2f pk_add(v2f a, v2f b) {
    v2f r; asm("v_pk_add_f32 %0, %1, %2" : "=v"(r) : "v"(a), "v"(b)); return r;
}
__device__ __forceinline__ v2f pk_mul(v2f a, v2f b) {
    v2f r; asm("v_pk_mul_f32 %0, %1, %2" : "=v"(r) : "v"(a), "v"(b)); return r;
}
__device__ __forceinline__ v2f pk_fma(v2f a, v2f b, v2f c) {
    v2f r; asm("v_pk_fma_f32 %0, %1, %2, %3" : "=v"(r) : "v"(a), "v"(b), "v"(c)); return r;
}

// DPP max step; bound_ctrl=true -> OOB reads 0.0f (all values >= 0).
template<int CTRL>
__device__ __forceinline__ float dpp_max_step(float x) {
    int s = __builtin_amdgcn_update_dpp(0, __float_as_int(x), CTRL, 0xf, 0xf, true);
    return fmaxf(x, __int_as_float(s));
}
// Full wave64 max on the VALU pipe; broadcast from lane 63.
__device__ __forceinline__ float wave_max_nn(float x) {
    x = dpp_max_step<0x111>(x);  // row_shr:1
    x = dpp_max_step<0x112>(x);  // row_shr:2
    x = dpp_max_step<0x114>(x);  // row_shr:4
    x = dpp_max_step<0x118>(x);  // row_shr:8
    x = dpp_max_step<0x142>(x);  // row_bcast:15
    x = dpp_max_step<0x143>(x);  // row_bcast:31
    return __int_as_float(__builtin_amdgcn_readlane(__float_as_int(x), 63));
}
__device__ __forceinline__ float readlane_f(float x, int l) {
    return __int_as_float(__builtin_amdgcn_readlane(__float_as_int(x), l));
}

// One block per batch, 256 threads x 32 points. NO global memory ops and NO
// barriers/fences inside the loop:
//  - selected indices accumulate in registers (thread t owns iterations
//    [16t,16t+16), statically indexed buf[16]); written once at the end.
//  - cross-wave sync = parity-double-buffered LDS mailbox, ONE relaxed
//    ds_write_b64 per wave per iter: [63:32]=dist_bits|[25:13]=idx|[12:0]=seq.
//    Tag and payload share the word -> no ordering fence needed. 2-phase
//    parity: a slot is rewritten only after every wave consumed it
//    (publish(s+1) happens after poll(s) completed). Data dependence (cidx
//    from the loaded word) orders the sx[cidx] reads.
// Distance math is the frozen XLA chain (bit-exact, validated R5/R7/R8/R10):
//   d = fma(dz,dz, fma(dy,dy, dx*dx))
// Ties: descending per-thread scan, ballot+ctz per wave, smallest slot per
// block (slot order == ascending point ranges) ==> exact numpy
// argmax-first-occurrence semantics.
__global__ __launch_bounds__(FPS_T, 1) void fps_kernel(
    const float* __restrict__ coords,
    const int*   __restrict__ init_idx,
    int*         __restrict__ out_idx,
    int M)
{
    __shared__ float sx[FPS_N], sy[FPS_N], sz[FPS_N];
    __shared__ u64 mbox[2][FPS_W];

    const int b    = blockIdx.x;
    const int tid  = threadIdx.x;
    const int lane = tid & 63;
    const int wv   = tid >> 6;
    const float* cb = coords + (size_t)b * FPS_N * 3;

    if (tid < 2 * FPS_W) ((u64*)mbox)[tid] = 0ull;   // no garbage tags

    // Load own 32 points: 96 contiguous floats = 24 float4 (coalesced)
    float f[96];
    const float4* cb4 = reinterpret_cast<const float4*>(cb);
    #pragma unroll
    for (int i = 0; i < 24; ++i) {
        float4 v = cb4[tid * 24 + i];
        f[i*4+0] = v.x; f[i*4+1] = v.y; f[i*4+2] = v.z; f[i*4+3] = v.w;
    }

    v2f px[FPS_PR], py[FPS_PR], pz[FPS_PR], dist[FPS_PR];
    const int base = tid * FPS_PPT;
    #pragma unroll
    for (int k = 0; k < FPS_PPT; ++k) {
        sx[base+k] = f[3*k+0]; sy[base+k] = f[3*k+1]; sz[base+k] = f[3*k+2];
    }
    #pragma unroll
    for (int j = 0; j < FPS_PR; ++j) {
        px[j] = v2f{f[6*j+0], f[6*j+3]};
        py[j] = v2f{f[6*j+1], f[6*j+4]};
        pz[j] = v2f{f[6*j+2], f[6*j+5]};
        dist[j] = v2f{1e8f, 1e8f};   // BIG, matches reference
    }
    __syncthreads();   // the only barrier: staging complete

    int far = init_idx[b];
    float cx = sx[far], cy = sy[far], cz = sz[far];

    int buf[16];   // statically-indexed (rule #20): stays in VGPRs
    #pragma unroll
    for (int i = 0; i < 16; ++i) buf[i] = 0;

    for (int so = 0; so < M; so += 16) {
        const int owner = so >> 4;   // thread owning these 16 iterations
        #pragma unroll
        for (int si = 0; si < 16; ++si) {
            const int s = so + si;
            if (tid == owner) buf[si] = far;   // record BEFORE update (reg!)

            // --- distance update + thread max (math frozen) ---
            const v2f ncx = v2f{-cx, -cx};   // a + (-c) == a - c, bit-exact
            const v2f ncy = v2f{-cy, -cy};
            const v2f ncz = v2f{-cz, -cz};
            float m = 0.0f;
            #pragma unroll
            for (int j = 0; j < FPS_PR; ++j) {
                v2f dx2 = pk_add(px[j], ncx);
                v2f dy2 = pk_add(py[j], ncy);
                v2f dz2 = pk_add(pz[j], ncz);
                v2f d2  = pk_fma(dz2, dz2, pk_fma(dy2, dy2, pk_mul(dx2, dx2)));
                v2f nd;
                nd.x = fminf(dist[j].x, d2.x);
                nd.y = fminf(dist[j].y, d2.y);
                dist[j] = nd;
                m = fmaxf(m, fmaxf(nd.x, nd.y));
            }
            // first index achieving m (descending scan -> smallest wins)
            int myidx = base;
            #pragma unroll
            for (int j = FPS_PR - 1; j >= 0; --j) {
                myidx = (dist[j].y == m) ? base + 2*j + 1 : myidx;
                myidx = (dist[j].x == m) ? base + 2*j     : myidx;
            }

            // --- stage 1: wave reduce (VALU pipe) ---
            float wm = wave_max_nn(m);
            u64 ball = __ballot(m == wm);
            int fl   = (int)__builtin_ctzll(ball);
            int widx = __builtin_amdgcn_readlane(myidx, fl);

            // --- publish: one relaxed 8B LDS write; tag==payload word ---
            const int par = s & 1;
            if (lane == 0) {
                u64 pk = ((u64)(unsigned)__float_as_uint(wm) << 32)
                       | ((u64)(unsigned)widx << 13)
                       | (u64)(unsigned)(s + 1);
                __hip_atomic_store(&mbox[par][wv], pk,
                                   __ATOMIC_RELAXED, __HIP_MEMORY_SCOPE_WORKGROUP);
            }

            // --- poll the 4 slots (lane i -> slot i&3) ---
            const unsigned tag = (unsigned)(s + 1);
            u64 v;
            do {
                v = __hip_atomic_load(&mbox[par][lane & (FPS_W - 1)],
                                      __ATOMIC_RELAXED, __HIP_MEMORY_SCOPE_WORKGROUP);
            } while (!__all((unsigned)(v & 0x1FFFull) == tag));

            // --- stage 2: reduce 4 candidates; speculative coord fetch ---
            float cand = __int_as_float((int)(v >> 32));
            int   cidx = (int)((v >> 13) & 0x1FFF);
            float fx = sx[cidx], fy = sy[cidx], fz = sz[cidx]; // overlaps reduce
            float g = cand;
            g = dpp_max_step<0x111>(g);   // row_shr:1
            g = dpp_max_step<0x112>(g);   // row_shr:2 -> lane 3 = max(s0..s3)
            float gm = readlane_f(g, 3);
            u64 b2 = __ballot(cand == gm);
            int l2 = (int)__builtin_ctzll(b2);  // winner slot bit set => l2<=3
            far = __builtin_amdgcn_readlane(cidx, l2);
            cx  = readlane_f(fx, l2);
            cy  = readlane_f(fy, l2);
            cz  = readlane_f(fz, l2);
        }
    }

    // Flush recorded indices: thread t wrote iterations [16t, 16t+16).
    int4* ob = reinterpret_cast<int4*>(out_idx + (size_t)b * M + tid * 16);
    ob[0] = int4{buf[0],  buf[1],  buf[2],  buf[3]};
    ob[1] = int4{buf[4],  buf[5],  buf[6],  buf[7]};
    ob[2] = int4{buf[8],  buf[9],  buf[10], buf[11]};
    ob[3] = int4{buf[12], buf[13], buf[14], buf[15]};
}

// One 64-thread block per output row: 64 x float4 = 256 floats of values,
// lanes 0-2 copy coords, lane 3 copies mask.
__global__ void gather_kernel(
    const float* __restrict__ coords,
    const float* __restrict__ values,
    const float* __restrict__ mask,
    const int*   __restrict__ idx,
    float* __restrict__ out_coords,
    float* __restrict__ out_values,
    float* __restrict__ out_mask,
    int N, int M, int D)
{
    const int bm = blockIdx.x;
    const int b  = bm / M;
    const int m  = bm - b * M;
    const int j  = idx[bm];
    const int l  = threadIdx.x;

    const float4* src = reinterpret_cast<const float4*>(values + ((size_t)b * N + j) * D);
    float4*       dst = reinterpret_cast<float4*>(out_values + ((size_t)b * M + m) * D);
    dst[l] = src[l];

    if (l < 3) {
        out_coords[((size_t)b * M + m) * 3 + l] = coords[((size_t)b * N + j) * 3 + l];
    } else if (l == 3) {
        out_mask[(size_t)b * M + m] = mask[(size_t)b * N + j];
    }
}

extern "C" void kernel_launch(void* const* d_in, const int* in_sizes, int n_in,
                              void* d_out, int out_size, void* d_ws, size_t ws_size,
                              hipStream_t stream)
{
    const float* coords   = (const float*)d_in[0];
    const float* values   = (const float*)d_in[1];
    const float* mask     = (const float*)d_in[2];
    const int*   init_idx = (const int*)d_in[3];

    const int B = in_sizes[3];
    const int N = in_sizes[2] / B;            // 8192
    const int D = in_sizes[1] / (B * N);      // 256
    const int M = N / 2;                      // SAMPLING_FRACTION = 0.5 -> 4096

    float* out_coords = (float*)d_out;
    float* out_values = out_coords + (size_t)B * M * 3;
    float* out_mask   = out_values + (size_t)B * M * D;

    int* idx = (int*)d_ws;   // B*M ints = 256 KB scratch

    fps_kernel<<<B, FPS_T, 0, stream>>>(coords, init_idx, idx, M);
    gather_kernel<<<B * M, D / 4, 0, stream>>>(coords, values, mask, idx,
                                               out_coords, out_values, out_mask,
                                               N, M, D);
}